// Round 5
// baseline (1681.840 us; speedup 1.0000x reference)
//
#include <hip/hip_runtime.h>

// RowSoftmax: out[e] = exp(leaky_relu(attr[e])) / rowsum[row[e]]
// R5 = R4 with the compile fix: records use a clang ext_vector (v2u) instead
// of HIP's uint2 class so __builtin_nontemporal_load/store accept them.
//  - single-pass binning, block-owned record regions (hist IS the cursor)
//  - 768 blocks, row/attr read once, LDS atomics halved vs R3
//  - regions 0..511 in ws, 512..767 alias d_out (accum before normalize)
//  - CAP=256 (mean 179 +5.8sigma); overflow spills via global atomicAdd
//    into zeroed spill[], folded into rownorm at accum (correct, slower).
#define N_NODES 1000000

#define BIN_SHIFT 12
#define BIN_NODES 4096               // nodes per bin -> 16KB LDS accum
#define NBINS 256                    // bins 0..244 populated (1e6/4096)
#define NBINS_REAL 245
#define NREGIONS 768
#define WS_REGIONS 512               // regions >= this live in d_out
#define CAP 256                      // records per (region,bin)
#define REGION_RECS (NBINS * CAP)    // 65536 recs = 512KB per region
#define RTHREADS 512

typedef int      v4i __attribute__((ext_vector_type(4)));
typedef float    v4f __attribute__((ext_vector_type(4)));
typedef unsigned v2u __attribute__((ext_vector_type(2)));

__device__ __forceinline__ float et_of(float x) {
    float lr = x >= 0.0f ? x : 0.01f * x;
    return __expf(lr);
}

// ---- single-pass reorder ------------------------------------------------
__global__ __launch_bounds__(RTHREADS) void reorder1p_kernel(
    const int* __restrict__ row, const float* __restrict__ attr,
    v2u* __restrict__ recA,          // ws regions [WS_REGIONS][REGION_RECS]
    v2u* __restrict__ recB,          // d_out regions [NREGIONS-WS_REGIONS][..]
    unsigned* __restrict__ cnt,      // [NREGIONS][NBINS]
    float* __restrict__ spill,       // [N_NODES], zeroed
    int E, int chunk)
{
    __shared__ unsigned hist[NBINS]; // doubles as allocation cursor
    for (int b = threadIdx.x; b < NBINS; b += blockDim.x) hist[b] = 0;
    __syncthreads();

    const int r = blockIdx.x;
    v2u* __restrict__ rec = (r < WS_REGIONS)
        ? recA + (size_t)r * REGION_RECS
        : recB + (size_t)(r - WS_REGIONS) * REGION_RECS;

    int start = r * chunk;
    int end   = min(start + chunk, E);
    int len   = end > start ? end - start : 0;
    int nvec  = len >> 2;

    for (int v = threadIdx.x; v < nvec; v += blockDim.x) {
        int idx = start + v * 4;
        v4i rr = __builtin_nontemporal_load(reinterpret_cast<const v4i*>(row + idx));
        v4f a  = __builtin_nontemporal_load(reinterpret_cast<const v4f*>(attr + idx));
#pragma unroll
        for (int k = 0; k < 4; ++k) {
            int nid = rr[k];
            int b   = nid >> BIN_SHIFT;
            float et = et_of(a[k]);
            unsigned rank = atomicAdd(&hist[b], 1u);
            if (rank < CAP) {
                v2u rc;
                rc.x = __float_as_uint(et);
                rc.y = (unsigned)(nid & (BIN_NODES - 1));
                rec[(size_t)b * CAP + rank] = rc;
            } else {
                atomicAdd(&spill[nid], et);   // rare (+5.8 sigma) but correct
            }
        }
    }
    for (int j = start + (nvec << 2) + threadIdx.x; j < end; j += blockDim.x) {
        int nid = row[j];
        int b   = nid >> BIN_SHIFT;
        float et = et_of(attr[j]);
        unsigned rank = atomicAdd(&hist[b], 1u);
        if (rank < CAP) {
            v2u rc;
            rc.x = __float_as_uint(et);
            rc.y = (unsigned)(nid & (BIN_NODES - 1));
            rec[(size_t)b * CAP + rank] = rc;
        } else {
            atomicAdd(&spill[nid], et);
        }
    }
    __syncthreads();

    for (int b = threadIdx.x; b < NBINS; b += blockDim.x)
        cnt[(size_t)r * NBINS + b] = min(hist[b], (unsigned)CAP);
}

// ---- accumulate: one bin per block, wave-per-region ---------------------
__global__ __launch_bounds__(1024) void accum1p_kernel(
    const v2u* __restrict__ recA, const v2u* __restrict__ recB,
    const unsigned* __restrict__ cnt,
    const float* __restrict__ spill,
    float* __restrict__ rownorm)
{
    __shared__ float acc[BIN_NODES];
    for (int j = threadIdx.x; j < BIN_NODES; j += blockDim.x) acc[j] = 0.0f;
    __syncthreads();

    const int b    = blockIdx.x;
    const int wave = threadIdx.x >> 6;
    const int lane = threadIdx.x & 63;
    const int nwaves = 1024 / 64;    // 16

    for (int r = wave; r < NREGIONS; r += nwaves) {
        unsigned n = cnt[(size_t)r * NBINS + b];
        const v2u* __restrict__ rec = (r < WS_REGIONS)
            ? recA + (size_t)r * REGION_RECS + (size_t)b * CAP
            : recB + (size_t)(r - WS_REGIONS) * REGION_RECS + (size_t)b * CAP;
        for (unsigned i = lane; i < n; i += 64) {
            v2u rc = __builtin_nontemporal_load(rec + i);
            atomicAdd(&acc[rc.y], __uint_as_float(rc.x));
        }
    }
    __syncthreads();

    int node0 = b << BIN_SHIFT;
    for (int j = threadIdx.x; j < BIN_NODES; j += blockDim.x) {
        int node = node0 + j;
        if (node < N_NODES)
            rownorm[node] = 1.0f / (acc[j] + spill[node]);
    }
}

// ---- normalize ----------------------------------------------------------
__global__ __launch_bounds__(256) void normalize_kernel(
    const int* __restrict__ row, const float* __restrict__ attr,
    const float* __restrict__ rownorm, float* __restrict__ out, int E)
{
    int i = (blockIdx.x * blockDim.x + threadIdx.x) * 4;
    if (i + 3 < E) {
        v4i r = __builtin_nontemporal_load(reinterpret_cast<const v4i*>(row + i));
        v4f a = __builtin_nontemporal_load(reinterpret_cast<const v4f*>(attr + i));
        v4f o;
        o.x = et_of(a.x) * rownorm[r.x];
        o.y = et_of(a.y) * rownorm[r.y];
        o.z = et_of(a.z) * rownorm[r.z];
        o.w = et_of(a.w) * rownorm[r.w];
        __builtin_nontemporal_store(o, reinterpret_cast<v4f*>(out + i));
    } else {
        for (; i < E; ++i)
            out[i] = et_of(attr[i]) * rownorm[row[i]];
    }
}

// ---- fallback tier (small ws): exact two-pass, split arrays -------------
#define FCHUNK 32768
#define FTHREADS 512

__global__ __launch_bounds__(FTHREADS) void count_kernel(
    const int* __restrict__ row, unsigned* __restrict__ bin_total, int E)
{
    __shared__ unsigned hist[NBINS];
    for (int b = threadIdx.x; b < NBINS; b += blockDim.x) hist[b] = 0;
    __syncthreads();
    int start = blockIdx.x * FCHUNK;
    int end   = min(start + FCHUNK, E);
    for (int j = start + threadIdx.x; j < end; j += blockDim.x)
        atomicAdd(&hist[row[j] >> BIN_SHIFT], 1u);
    __syncthreads();
    for (int b = threadIdx.x; b < NBINS; b += blockDim.x) {
        unsigned c = hist[b];
        if (c) atomicAdd(&bin_total[b], c);
    }
}

__global__ __launch_bounds__(NBINS) void scan_kernel(
    const unsigned* __restrict__ bin_total,
    unsigned* __restrict__ cursor,
    unsigned* __restrict__ bin_base)
{
    __shared__ unsigned s[NBINS];
    int t = threadIdx.x;
    unsigned mine = bin_total[t];
    s[t] = mine;
    __syncthreads();
    for (int off = 1; off < NBINS; off <<= 1) {
        unsigned add = (t >= off) ? s[t - off] : 0u;
        __syncthreads();
        s[t] += add;
        __syncthreads();
    }
    unsigned excl = s[t] - mine;
    cursor[t]   = excl;
    bin_base[t] = excl;
    if (t == NBINS - 1) bin_base[NBINS] = s[t];
}

__global__ __launch_bounds__(FTHREADS) void reorder_split_kernel(
    const int* __restrict__ row, const float* __restrict__ attr,
    unsigned* __restrict__ cursor,
    float* __restrict__ etArr, unsigned short* __restrict__ rl,
    int E, int chunk)
{
    __shared__ unsigned hist[NBINS];
    __shared__ unsigned base[NBINS];
    for (int b = threadIdx.x; b < NBINS; b += blockDim.x) hist[b] = 0;
    __syncthreads();
    int start = blockIdx.x * chunk;
    int end   = min(start + chunk, E);
    for (int j = start + threadIdx.x; j < end; j += blockDim.x)
        atomicAdd(&hist[row[j] >> BIN_SHIFT], 1u);
    __syncthreads();
    for (int b = threadIdx.x; b < NBINS; b += blockDim.x) {
        unsigned c = hist[b];
        base[b] = c ? atomicAdd(&cursor[b], c) : 0u;
        hist[b] = 0;
    }
    __syncthreads();
    for (int j = start + threadIdx.x; j < end; j += blockDim.x) {
        int nid = row[j];
        int b   = nid >> BIN_SHIFT;
        unsigned rank = atomicAdd(&hist[b], 1u);
        unsigned pos  = base[b] + rank;
        etArr[pos] = et_of(attr[j]);
        rl[pos]    = (unsigned short)(nid & (BIN_NODES - 1));
    }
}

__global__ __launch_bounds__(512) void accum_split_kernel(
    const float* __restrict__ etArr, const unsigned short* __restrict__ rl,
    const unsigned* __restrict__ bin_start,
    const unsigned* __restrict__ bin_end,
    float* __restrict__ rownorm)
{
    __shared__ float acc[BIN_NODES];
    for (int j = threadIdx.x; j < BIN_NODES; j += blockDim.x) acc[j] = 0.0f;
    __syncthreads();
    int b = blockIdx.x;
    unsigned s = bin_start[b], e = bin_end[b];
    for (unsigned i = s + threadIdx.x; i < e; i += blockDim.x)
        atomicAdd(&acc[rl[i]], etArr[i]);
    __syncthreads();
    int node0 = b << BIN_SHIFT;
    for (int j = threadIdx.x; j < BIN_NODES; j += blockDim.x) {
        int node = node0 + j;
        if (node < N_NODES) rownorm[node] = 1.0f / acc[j];
    }
}

extern "C" void kernel_launch(void* const* d_in, const int* in_sizes, int n_in,
                              void* d_out, int out_size, void* d_ws, size_t ws_size,
                              hipStream_t stream) {
    const int*   edge_index = (const int*)d_in[0];   // (2,E) int32; row = first E
    const float* attr       = (const float*)d_in[1]; // (E,) float32
    const int    E          = in_sizes[1];

    const int* row = edge_index;
    float* out     = (float*)d_out;
    char* ws       = (char*)d_ws;

    const int threads  = 256;
    const int blocksE4 = (E + threads * 4 - 1) / (threads * 4);

    auto align64 = [](size_t x) { return (x + 63) & ~(size_t)63; };

    // layout: recA | cnt | spill | rownorm
    size_t o_recA    = 0;
    size_t o_cnt     = align64(o_recA + (size_t)WS_REGIONS * REGION_RECS * 8);
    size_t o_spill   = align64(o_cnt + (size_t)NREGIONS * NBINS * 4);
    size_t o_rownorm = align64(o_spill + (size_t)N_NODES * 4);
    size_t need      = o_rownorm + (size_t)N_NODES * 4;

    // d_out must hold the (NREGIONS - WS_REGIONS) overflow regions.
    size_t outb_need = (size_t)(NREGIONS - WS_REGIONS) * REGION_RECS * 8;

    if (ws_size >= need && (size_t)out_size >= outb_need) {
        v2u*      recA    = (v2u*)(ws + o_recA);
        v2u*      recB    = (v2u*)d_out;
        unsigned* cnt     = (unsigned*)(ws + o_cnt);
        float*    spill   = (float*)(ws + o_spill);
        float*    rownorm = (float*)(ws + o_rownorm);

        (void)hipMemsetAsync(spill, 0, (size_t)N_NODES * sizeof(float), stream);

        int chunk = ((E + NREGIONS - 1) / NREGIONS + 3) & ~3;
        reorder1p_kernel<<<NREGIONS, RTHREADS, 0, stream>>>(
            row, attr, recA, recB, cnt, spill, E, chunk);
        accum1p_kernel<<<NBINS_REAL, 1024, 0, stream>>>(
            recA, recB, cnt, spill, rownorm);
        normalize_kernel<<<blocksE4, threads, 0, stream>>>(
            row, attr, rownorm, out, E);
    } else {
        // fallback: exact two-pass, et in d_out, rl ushort in ws (~71MB)
        size_t f_rl      = 0;
        size_t f_rownorm = align64(f_rl + (size_t)E * 2);
        size_t f_total   = align64(f_rownorm + (size_t)N_NODES * 4);
        size_t f_cursor  = align64(f_total + NBINS * 4);
        size_t f_base    = align64(f_cursor + NBINS * 4);

        unsigned short* rl  = (unsigned short*)(ws + f_rl);
        float* rownorm      = (float*)(ws + f_rownorm);
        unsigned* bin_total = (unsigned*)(ws + f_total);
        unsigned* cursor    = (unsigned*)(ws + f_cursor);
        unsigned* bin_base  = (unsigned*)(ws + f_base);
        float* etArr        = out;

        (void)hipMemsetAsync(bin_total, 0, NBINS * sizeof(unsigned), stream);
        const int blocksC = (E + FCHUNK - 1) / FCHUNK;
        count_kernel<<<blocksC, FTHREADS, 0, stream>>>(row, bin_total, E);
        scan_kernel<<<1, NBINS, 0, stream>>>(bin_total, cursor, bin_base);
        const int rblocks = 512;
        int chunk = ((E + rblocks - 1) / rblocks + 3) & ~3;
        reorder_split_kernel<<<rblocks, FTHREADS, 0, stream>>>(
            row, attr, cursor, etArr, rl, E, chunk);
        accum_split_kernel<<<NBINS, 512, 0, stream>>>(
            etArr, rl, bin_base, bin_base + 1, rownorm);
        normalize_kernel<<<blocksE4, threads, 0, stream>>>(
            row, attr, rownorm, out, E);
    }
}